// Round 8
// baseline (95.817 us; speedup 1.0000x reference)
//
#include <hip/hip_runtime.h>
#include <math.h>

// Problem constants (reference: N=250000, D=16, L=6, K=64, gamma=0.1)
#define NPOINTS 250000
#define LL 6
#define DD 16
#define KK 64

// R19: 4 B-tiles (64 points) per wave. R7 confirmed the regime: per-wave
// dependency latency is the wall; 1->2 chains was 44->37us. 4 independent
// MFMA->poly->exp->reduce chains per layer; Am/aa loads, log2, and the
// F-recurrence amortize over 4x points. TPB=128 -> 1954 blocks (no grid tail).
#define TPB 128
#define WAVES_PER_BLOCK (TPB / 64)
#define PTS_PER_WAVE 64
#define PTS_PER_BLOCK (WAVES_PER_BLOCK * PTS_PER_WAVE)   // 128

// LDS: per-wave x staging: 64 points * 80 B (32 hi + 32 lo + 16 pad)
#define LDS_BYTES (WAVES_PER_BLOCK * PTS_PER_WAVE * 80)  // 10240

// d_ws layout (bytes):
//  WS_MU: column (l*64+k) as 64 B = 32 B bf16-hi + 32 B bf16-lo, pre-scaled -1/2
//  WS_AV: av[l*64+k] = C_AA*alpha - W0
//  WS_WV: exp(-ws^2) per layer
#define WS_MU 0
#define WS_AV 24576
#define WS_WV 26112

typedef __attribute__((ext_vector_type(8))) short bf16x8;
typedef __attribute__((ext_vector_type(4))) float f32x4;
typedef __attribute__((ext_vector_type(2))) float f32x2;

#if __has_builtin(__builtin_amdgcn_exp2f)
#define EXP2F(x) __builtin_amdgcn_exp2f(x)
#else
#define EXP2F(x) exp2f(x)
#endif
#if __has_builtin(__builtin_amdgcn_logf)
#define LOG2F(x) __builtin_amdgcn_logf(x)
#else
#define LOG2F(x) log2f(x)
#endif

#define C_AA   (-14.426950408889634f)   // -10 * log2(e)
#define C_GLN2 (0.06931471805599453f)   // gamma * ln(2)

// Fused distance->log2 term: with mu pre-scaled by -1/2, MFMA emits x' = -ip/2
// and t2 = (aa - w0) + x'*Vt(x').  Vt = degree-5 poly (error budget: |err(F)|
// <= ~2.6e-4).  Estrin evaluation.
#define W0  17.797117f
#define VT0 (-45.300328f)
#define VT1 (-28.559404f)
#define VT2 (-27.844414f)
#define VT3 (-30.475230f)
#define VT4 (-36.246253f)
#define VT5 (-27.207285f)

__device__ __forceinline__ f32x2 s2(float v) { f32x2 r; r.x = v; r.y = v; return r; }

__device__ __forceinline__ ushort bf16_rne(float f) {
  unsigned u = __float_as_uint(f);
  unsigned r = u + 0x7FFFu + ((u >> 16) & 1u);
  return (ushort)(r >> 16);
}

// packed pair: exp2( (aa-w0) + xp*Vt(xp) ), xp = -ip/2 from MFMA.  Estrin:
// Vt = P01 + xp^2*(P23 + xp^2*P45), Pij = VTi + VTj*xp.
__device__ __forceinline__ f32x2 term2(f32x2 xp, f32x2 aaw) {
  f32x2 x2  = xp * xp;
  f32x2 p01 = __builtin_elementwise_fma(s2(VT1), xp, s2(VT0));
  f32x2 p23 = __builtin_elementwise_fma(s2(VT3), xp, s2(VT2));
  f32x2 p45 = __builtin_elementwise_fma(s2(VT5), xp, s2(VT4));
  f32x2 qq  = __builtin_elementwise_fma(x2, p45, p23);
  f32x2 V   = __builtin_elementwise_fma(x2, qq, p01);
  f32x2 t2  = __builtin_elementwise_fma(xp, V, aaw);
  f32x2 e; e.x = EXP2F(t2.x); e.y = EXP2F(t2.y);
  return e;
}

// pack one float4 (dims 4q..4q+3) of a point into bf16 hi/lo at dst
__device__ __forceinline__ void pack_pt(char* dst, float4 a, int q) {
  ushort h0 = bf16_rne(a.x), h1 = bf16_rne(a.y);
  ushort h2 = bf16_rne(a.z), h3 = bf16_rne(a.w);
  float hf0 = __uint_as_float((unsigned)h0 << 16);
  float hf1 = __uint_as_float((unsigned)h1 << 16);
  float hf2 = __uint_as_float((unsigned)h2 << 16);
  float hf3 = __uint_as_float((unsigned)h3 << 16);
  ushort l0 = bf16_rne(a.x - hf0), l1 = bf16_rne(a.y - hf1);
  ushort l2 = bf16_rne(a.z - hf2), l3 = bf16_rne(a.w - hf3);
  uint2 hwv, lwv;
  hwv.x = (unsigned)h0 | ((unsigned)h1 << 16);
  hwv.y = (unsigned)h2 | ((unsigned)h3 << 16);
  lwv.x = (unsigned)l0 | ((unsigned)l1 << 16);
  lwv.y = (unsigned)l2 | ((unsigned)l3 << 16);
  *(uint2*)(dst + q * 8) = hwv;        // hi words 2q,2q+1
  *(uint2*)(dst + 32 + q * 8) = lwv;   // lo words 2q,2q+1
}

// ---- prep kernel: 1 block, 384 threads; thread t = (layer l, comp k) ----
__global__ __launch_bounds__(384) void
prep_kernel(const float* __restrict__ mus,    // [L, D, K]
            const float* __restrict__ alphas, // [L, K]
            const float* __restrict__ wsv,    // [L]
            char* __restrict__ ws) {
  const int t = threadIdx.x;          // 0..383 == l*64+k
  const float* colp = mus + (t >> 6) * (DD * KK) + (t & 63);
  float v[DD];
  float ss = 0.0f;
#pragma unroll
  for (int d = 0; d < DD; ++d) { v[d] = colp[d * KK]; ss = fmaf(v[d], v[d], ss); }
  float inv = -0.5f / sqrtf(ss);      // normalize AND scale by -1/2 (exact scale)
  unsigned hw[8], lw[8];
#pragma unroll
  for (int i = 0; i < 8; ++i) {
    float a0 = v[2 * i] * inv;
    float a1 = v[2 * i + 1] * inv;
    ushort h0 = bf16_rne(a0), h1 = bf16_rne(a1);
    float hf0 = __uint_as_float((unsigned)h0 << 16);
    float hf1 = __uint_as_float((unsigned)h1 << 16);
    ushort l0 = bf16_rne(a0 - hf0), l1 = bf16_rne(a1 - hf1);
    hw[i] = (unsigned)h0 | ((unsigned)h1 << 16);
    lw[i] = (unsigned)l0 | ((unsigned)l1 << 16);
  }
  uint4* colq = (uint4*)(ws + WS_MU + t * 64);
  colq[0] = make_uint4(hw[0], hw[1], hw[2], hw[3]);
  colq[1] = make_uint4(hw[4], hw[5], hw[6], hw[7]);
  colq[2] = make_uint4(lw[0], lw[1], lw[2], lw[3]);
  colq[3] = make_uint4(lw[4], lw[5], lw[6], lw[7]);
  ((float*)(ws + WS_AV))[t] = fmaf(C_AA, alphas[t], -W0);
  if (t < LL) { float x = wsv[t]; ((float*)(ws + WS_WV))[t] = expf(-x * x); }
}

__global__ __launch_bounds__(TPB, 4) void
multiinf_kernel(const float* __restrict__ xs,
                const char* __restrict__ ws,
                float* __restrict__ out) {
  __shared__ __align__(16) char smem[LDS_BYTES];

  const int tid = threadIdx.x;
  const int wid = tid >> 6;          // wave in block
  const int lane = tid & 63;
  const int c = lane & 15;           // MFMA col: point-in-tile (comp idx for A read)
  const int q = lane >> 4;           // quad
  const int h = q & 1;               // dim half for B (x) reads
  const int pt0 = blockIdx.x * PTS_PER_BLOCK + wid * PTS_PER_WAVE;
  char* sx = smem + wid * (PTS_PER_WAVE * 80);

  // ---- Stage this wave's 64 points: lane (c,q) loads points c+16t, t=0..3,
  //      dims 4q..4q+3 each, packs bf16 hi/lo. Same-wave LDS dep only.
#pragma unroll
  for (int t = 0; t < 4; ++t) {
    int p = pt0 + 16 * t + c;
    float4 a = make_float4(0.0f, 0.0f, 0.0f, 0.0f);
    if (p < NPOINTS) a = ((const float4*)(xs + (size_t)p * DD))[q];
    pack_pt(sx + (16 * t + c) * 80, a, q);
  }

  // B fragments: LOOP-INVARIANT across all 6 layers; four tiles per wave.
  bf16x8 Bh0 = *(const bf16x8*)(sx + (c) * 80 + h * 16);
  bf16x8 Bl0 = *(const bf16x8*)(sx + (c) * 80 + 32 + h * 16);
  bf16x8 Bh1 = *(const bf16x8*)(sx + (16 + c) * 80 + h * 16);
  bf16x8 Bl1 = *(const bf16x8*)(sx + (16 + c) * 80 + 32 + h * 16);
  bf16x8 Bh2 = *(const bf16x8*)(sx + (32 + c) * 80 + h * 16);
  bf16x8 Bl2 = *(const bf16x8*)(sx + (32 + c) * 80 + 32 + h * 16);
  bf16x8 Bh3 = *(const bf16x8*)(sx + (48 + c) * 80 + h * 16);
  bf16x8 Bl3 = *(const bf16x8*)(sx + (48 + c) * 80 + 32 + h * 16);

  const float* swv = (const float*)(ws + WS_WV);
  const f32x4 zero4 = {0.0f, 0.0f, 0.0f, 0.0f};
  float F0 = 0.0f, F1 = 0.0f, F2 = 0.0f, F3 = 0.0f;

#pragma unroll 1
  for (int l = 0; l < LL; ++l) {
    // per-layer mu fragments + constants (ws is L1/L2-hot, 24.5 KB total)
    bf16x8 Am[4];
    f32x2 aaL[4], aaH[4];
#pragma unroll
    for (int cb = 0; cb < 4; ++cb) {
      Am[cb] = *(const bf16x8*)(ws + WS_MU + (l * 64 + cb * 16 + c) * 64 + q * 16);
      f32x4 a4 = *(const f32x4*)(ws + WS_AV + (l * 64 + cb * 16 + q * 4) * 4);
      aaL[cb].x = a4.x; aaL[cb].y = a4.y;
      aaH[cb].x = a4.z; aaH[cb].y = a4.w;
    }
    f32x2 S01a = s2(0.0f), S23a = s2(0.0f);
    f32x2 S01b = s2(0.0f), S23b = s2(0.0f);
    f32x2 S01c = s2(0.0f), S23c = s2(0.0f);
    f32x2 S01d = s2(0.0f), S23d = s2(0.0f);
#pragma unroll
    for (int cb = 0; cb < 4; ++cb) {
      f32x4 accA = __builtin_amdgcn_mfma_f32_16x16x32_bf16(Am[cb], Bh0, zero4, 0, 0, 0);
      accA = __builtin_amdgcn_mfma_f32_16x16x32_bf16(Am[cb], Bl0, accA, 0, 0, 0);
      f32x4 accB = __builtin_amdgcn_mfma_f32_16x16x32_bf16(Am[cb], Bh1, zero4, 0, 0, 0);
      accB = __builtin_amdgcn_mfma_f32_16x16x32_bf16(Am[cb], Bl1, accB, 0, 0, 0);
      f32x4 accC = __builtin_amdgcn_mfma_f32_16x16x32_bf16(Am[cb], Bh2, zero4, 0, 0, 0);
      accC = __builtin_amdgcn_mfma_f32_16x16x32_bf16(Am[cb], Bl2, accC, 0, 0, 0);
      f32x4 accD = __builtin_amdgcn_mfma_f32_16x16x32_bf16(Am[cb], Bh3, zero4, 0, 0, 0);
      accD = __builtin_amdgcn_mfma_f32_16x16x32_bf16(Am[cb], Bl3, accD, 0, 0, 0);
      f32x2 t01, t23;
      t01.x = accA[0]; t01.y = accA[1]; t23.x = accA[2]; t23.y = accA[3];
      S01a += term2(t01, aaL[cb]);
      S23a += term2(t23, aaH[cb]);
      t01.x = accB[0]; t01.y = accB[1]; t23.x = accB[2]; t23.y = accB[3];
      S01b += term2(t01, aaL[cb]);
      S23b += term2(t23, aaH[cb]);
      t01.x = accC[0]; t01.y = accC[1]; t23.x = accC[2]; t23.y = accC[3];
      S01c += term2(t01, aaL[cb]);
      S23c += term2(t23, aaH[cb]);
      t01.x = accD[0]; t01.y = accD[1]; t23.x = accD[2]; t23.y = accD[3];
      S01d += term2(t01, aaL[cb]);
      S23d += term2(t23, aaH[cb]);
    }
    f32x2 Sfa = S01a + S23a;
    f32x2 Sfb = S01b + S23b;
    f32x2 Sfc = S01c + S23c;
    f32x2 Sfd = S01d + S23d;
    float St0 = Sfa.x + Sfa.y;
    float St1 = Sfb.x + Sfb.y;
    float St2 = Sfc.x + Sfc.y;
    float St3 = Sfd.x + Sfd.y;
    St0 += __shfl_xor(St0, 16, 64);
    St0 += __shfl_xor(St0, 32, 64);
    St1 += __shfl_xor(St1, 16, 64);
    St1 += __shfl_xor(St1, 32, 64);
    St2 += __shfl_xor(St2, 16, 64);
    St2 += __shfl_xor(St2, 32, 64);
    St3 += __shfl_xor(St3, 16, 64);
    St3 += __shfl_xor(St3, 32, 64);
    float wvl = swv[l];
    float mc0 = C_GLN2 * LOG2F(St0);  // gamma*ln(S)
    float mc1 = C_GLN2 * LOG2F(St1);
    float mc2 = C_GLN2 * LOG2F(St2);
    float mc3 = C_GLN2 * LOG2F(St3);
    float om = 1.0f - wvl;
    F0 = fmaf(wvl, fmaxf(F0, 0.0f), om * mc0);
    F1 = fmaf(wvl, fmaxf(F1, 0.0f), om * mc1);
    F2 = fmaf(wvl, fmaxf(F2, 0.0f), om * mc2);
    F3 = fmaf(wvl, fmaxf(F3, 0.0f), om * mc3);
  }

  // ---- smooth-min + store: lane owns point pt0+lane (tile = lane>>4) ----
  {
    int t = lane >> 4;   // wave-uniform per 16-lane group
    float Fv = (t == 0) ? F0 : (t == 1) ? F1 : (t == 2) ? F2 : F3;
    int idx = pt0 + lane;
    if (idx < NPOINTS) {
      float e = EXP2F(Fv * C_AA);             // exp(-F/0.1)
      out[idx] = C_GLN2 * LOG2F(1.0f + e);    // 0.1 * ln(1 + e)
    }
  }
}

extern "C" void kernel_launch(void* const* d_in, const int* in_sizes, int n_in,
                              void* d_out, int out_size, void* d_ws, size_t ws_size,
                              hipStream_t stream) {
  const float* xs = (const float*)d_in[0];     // [N, D]
  const float* mus = (const float*)d_in[1];    // [L, D, K]
  const float* alphas = (const float*)d_in[2]; // [L, K]
  const float* wsv = (const float*)d_in[3];    // [L]
  float* out = (float*)d_out;
  char* ws = (char*)d_ws;
  (void)ws_size;

  prep_kernel<<<1, 384, 0, stream>>>(mus, alphas, wsv, ws);
  const int blocks = (NPOINTS + PTS_PER_BLOCK - 1) / PTS_PER_BLOCK;  // 1954
  multiinf_kernel<<<blocks, TPB, 0, stream>>>(xs, ws, out);
}

// Round 9
// 95.606 us; speedup vs baseline: 1.0022x; 1.0022x over previous
//
#include <hip/hip_runtime.h>
#include <math.h>

// Problem constants (reference: N=250000, D=16, L=6, K=64, gamma=0.1)
#define NPOINTS 250000
#define LL 6
#define DD 16
#define KK 64

// R20: stage-batched pipes + scheduler headroom. R8 evidence: per-wave issue
// ~10K/89K cycles (one instr per ~9 cyc) => asm stream re-serialized by the
// 128-VGPR budget. Fix: (1) launch_bounds (128,3) -> 168 VGPR; (2) per-cb
// explicit stages (8 MFMA -> 8 pk-poly -> 16 exp -> 8 add) so trans/VALU
// pipes batch; (3) double-buffered Am prefetch across layers.
#define TPB 128
#define WAVES_PER_BLOCK (TPB / 64)
#define PTS_PER_WAVE 64
#define PTS_PER_BLOCK (WAVES_PER_BLOCK * PTS_PER_WAVE)   // 128

// LDS: per-wave x staging: 64 points * 80 B (32 hi + 32 lo + 16 pad)
#define LDS_BYTES (WAVES_PER_BLOCK * PTS_PER_WAVE * 80)  // 10240

// d_ws layout (bytes):
//  WS_MU: column (l*64+k) as 64 B = 32 B bf16-hi + 32 B bf16-lo, pre-scaled -1/2
//  WS_AV: av[l*64+k] = C_AA*alpha - W0
//  WS_WV: exp(-ws^2) per layer
#define WS_MU 0
#define WS_AV 24576
#define WS_WV 26112

typedef __attribute__((ext_vector_type(8))) short bf16x8;
typedef __attribute__((ext_vector_type(4))) float f32x4;
typedef __attribute__((ext_vector_type(2))) float f32x2;

#if __has_builtin(__builtin_amdgcn_exp2f)
#define EXP2F(x) __builtin_amdgcn_exp2f(x)
#else
#define EXP2F(x) exp2f(x)
#endif
#if __has_builtin(__builtin_amdgcn_logf)
#define LOG2F(x) __builtin_amdgcn_logf(x)
#else
#define LOG2F(x) log2f(x)
#endif

#define C_AA   (-14.426950408889634f)   // -10 * log2(e)
#define C_GLN2 (0.06931471805599453f)   // gamma * ln(2)

// Fused distance->log2 term: with mu pre-scaled by -1/2, MFMA emits x' = -ip/2
// and t2 = (aa - w0) + x'*Vt(x').  Vt = degree-5 poly (error budget: |err(F)|
// <= ~2.6e-4).  Estrin evaluation.
#define W0  17.797117f
#define VT0 (-45.300328f)
#define VT1 (-28.559404f)
#define VT2 (-27.844414f)
#define VT3 (-30.475230f)
#define VT4 (-36.246253f)
#define VT5 (-27.207285f)

__device__ __forceinline__ f32x2 s2(float v) { f32x2 r; r.x = v; r.y = v; return r; }

__device__ __forceinline__ ushort bf16_rne(float f) {
  unsigned u = __float_as_uint(f);
  unsigned r = u + 0x7FFFu + ((u >> 16) & 1u);
  return (ushort)(r >> 16);
}

// t2 = aaw + xp*Vt(xp), Estrin: Vt = P01 + xp^2*(P23 + xp^2*P45)
__device__ __forceinline__ f32x2 poly_t2(f32x2 xp, f32x2 aaw) {
  f32x2 x2  = xp * xp;
  f32x2 p01 = __builtin_elementwise_fma(s2(VT1), xp, s2(VT0));
  f32x2 p23 = __builtin_elementwise_fma(s2(VT3), xp, s2(VT2));
  f32x2 p45 = __builtin_elementwise_fma(s2(VT5), xp, s2(VT4));
  f32x2 qq  = __builtin_elementwise_fma(x2, p45, p23);
  f32x2 V   = __builtin_elementwise_fma(x2, qq, p01);
  return __builtin_elementwise_fma(xp, V, aaw);
}

// pack one float4 (dims 4q..4q+3) of a point into bf16 hi/lo at dst
__device__ __forceinline__ void pack_pt(char* dst, float4 a, int q) {
  ushort h0 = bf16_rne(a.x), h1 = bf16_rne(a.y);
  ushort h2 = bf16_rne(a.z), h3 = bf16_rne(a.w);
  float hf0 = __uint_as_float((unsigned)h0 << 16);
  float hf1 = __uint_as_float((unsigned)h1 << 16);
  float hf2 = __uint_as_float((unsigned)h2 << 16);
  float hf3 = __uint_as_float((unsigned)h3 << 16);
  ushort l0 = bf16_rne(a.x - hf0), l1 = bf16_rne(a.y - hf1);
  ushort l2 = bf16_rne(a.z - hf2), l3 = bf16_rne(a.w - hf3);
  uint2 hwv, lwv;
  hwv.x = (unsigned)h0 | ((unsigned)h1 << 16);
  hwv.y = (unsigned)h2 | ((unsigned)h3 << 16);
  lwv.x = (unsigned)l0 | ((unsigned)l1 << 16);
  lwv.y = (unsigned)l2 | ((unsigned)l3 << 16);
  *(uint2*)(dst + q * 8) = hwv;        // hi words 2q,2q+1
  *(uint2*)(dst + 32 + q * 8) = lwv;   // lo words 2q,2q+1
}

// ---- prep kernel: 1 block, 384 threads; thread t = (layer l, comp k) ----
__global__ __launch_bounds__(384) void
prep_kernel(const float* __restrict__ mus,    // [L, D, K]
            const float* __restrict__ alphas, // [L, K]
            const float* __restrict__ wsv,    // [L]
            char* __restrict__ ws) {
  const int t = threadIdx.x;          // 0..383 == l*64+k
  const float* colp = mus + (t >> 6) * (DD * KK) + (t & 63);
  float v[DD];
  float ss = 0.0f;
#pragma unroll
  for (int d = 0; d < DD; ++d) { v[d] = colp[d * KK]; ss = fmaf(v[d], v[d], ss); }
  float inv = -0.5f / sqrtf(ss);      // normalize AND scale by -1/2 (exact scale)
  unsigned hw[8], lw[8];
#pragma unroll
  for (int i = 0; i < 8; ++i) {
    float a0 = v[2 * i] * inv;
    float a1 = v[2 * i + 1] * inv;
    ushort h0 = bf16_rne(a0), h1 = bf16_rne(a1);
    float hf0 = __uint_as_float((unsigned)h0 << 16);
    float hf1 = __uint_as_float((unsigned)h1 << 16);
    ushort l0 = bf16_rne(a0 - hf0), l1 = bf16_rne(a1 - hf1);
    hw[i] = (unsigned)h0 | ((unsigned)h1 << 16);
    lw[i] = (unsigned)l0 | ((unsigned)l1 << 16);
  }
  uint4* colq = (uint4*)(ws + WS_MU + t * 64);
  colq[0] = make_uint4(hw[0], hw[1], hw[2], hw[3]);
  colq[1] = make_uint4(hw[4], hw[5], hw[6], hw[7]);
  colq[2] = make_uint4(lw[0], lw[1], lw[2], lw[3]);
  colq[3] = make_uint4(lw[4], lw[5], lw[6], lw[7]);
  ((float*)(ws + WS_AV))[t] = fmaf(C_AA, alphas[t], -W0);
  if (t < LL) { float x = wsv[t]; ((float*)(ws + WS_WV))[t] = expf(-x * x); }
}

__global__ __launch_bounds__(TPB, 3) void
multiinf_kernel(const float* __restrict__ xs,
                const char* __restrict__ ws,
                float* __restrict__ out) {
  __shared__ __align__(16) char smem[LDS_BYTES];

  const int tid = threadIdx.x;
  const int wid = tid >> 6;          // wave in block
  const int lane = tid & 63;
  const int c = lane & 15;           // MFMA col: point-in-tile (comp idx for A read)
  const int q = lane >> 4;           // quad
  const int h = q & 1;               // dim half for B (x) reads
  const int pt0 = blockIdx.x * PTS_PER_BLOCK + wid * PTS_PER_WAVE;
  char* sx = smem + wid * (PTS_PER_WAVE * 80);

  // ---- Stage this wave's 64 points (same-wave LDS dep only, no barrier) ----
#pragma unroll
  for (int t = 0; t < 4; ++t) {
    int p = pt0 + 16 * t + c;
    float4 a = make_float4(0.0f, 0.0f, 0.0f, 0.0f);
    if (p < NPOINTS) a = ((const float4*)(xs + (size_t)p * DD))[q];
    pack_pt(sx + (16 * t + c) * 80, a, q);
  }

  // B fragments: loop-invariant; four tiles per wave.
  bf16x8 Bh[4], Bl[4];
#pragma unroll
  for (int t = 0; t < 4; ++t) {
    Bh[t] = *(const bf16x8*)(sx + (16 * t + c) * 80 + h * 16);
    Bl[t] = *(const bf16x8*)(sx + (16 * t + c) * 80 + 32 + h * 16);
  }

  const float* swv = (const float*)(ws + WS_WV);
  const f32x4 zero4 = {0.0f, 0.0f, 0.0f, 0.0f};
  float F[4] = {0.0f, 0.0f, 0.0f, 0.0f};

  // Am loaders (16 B/lane x 4 cb). aa loaded per-layer (not double-buffered).
  auto load_Am = [&](int l, bf16x8* Am) {
#pragma unroll
    for (int cb = 0; cb < 4; ++cb)
      Am[cb] = *(const bf16x8*)(ws + WS_MU + (l * 64 + cb * 16 + c) * 64 + q * 16);
  };
  auto load_aa = [&](int l, f32x2* aaL, f32x2* aaH) {
#pragma unroll
    for (int cb = 0; cb < 4; ++cb) {
      f32x4 a4 = *(const f32x4*)(ws + WS_AV + (l * 64 + cb * 16 + q * 4) * 4);
      aaL[cb].x = a4.x; aaL[cb].y = a4.y;
      aaH[cb].x = a4.z; aaH[cb].y = a4.w;
    }
  };

  // One layer: stage-batched. 8 MFMA -> 8 pk-poly -> 16 exp -> 8 add per cb.
  auto layer_body = [&](int l, const bf16x8* Am) {
    f32x2 aaL[4], aaH[4];
    load_aa(l, aaL, aaH);
    f32x2 S[8];
#pragma unroll
    for (int i = 0; i < 8; ++i) S[i] = s2(0.0f);
#pragma unroll
    for (int cb = 0; cb < 4; ++cb) {
      // stage 1: 8 MFMAs (4 independent hi->lo pairs)
      f32x4 acc[4];
#pragma unroll
      for (int t = 0; t < 4; ++t) {
        acc[t] = __builtin_amdgcn_mfma_f32_16x16x32_bf16(Am[cb], Bh[t], zero4, 0, 0, 0);
        acc[t] = __builtin_amdgcn_mfma_f32_16x16x32_bf16(Am[cb], Bl[t], acc[t], 0, 0, 0);
      }
      // stage 2: 8 packed polys
      f32x2 t2[8];
#pragma unroll
      for (int t = 0; t < 4; ++t) {
        f32x2 x01, x23;
        x01.x = acc[t][0]; x01.y = acc[t][1];
        x23.x = acc[t][2]; x23.y = acc[t][3];
        t2[2 * t]     = poly_t2(x01, aaL[cb]);
        t2[2 * t + 1] = poly_t2(x23, aaH[cb]);
      }
      // stage 3: 16 exps back-to-back (trans pipe batches)
      f32x2 e[8];
#pragma unroll
      for (int i = 0; i < 8; ++i) { e[i].x = EXP2F(t2[i].x); e[i].y = EXP2F(t2[i].y); }
      // stage 4: 8 accumulates
#pragma unroll
      for (int i = 0; i < 8; ++i) S[i] += e[i];
    }
    // tail: per-tile reduce + log + recurrence
    float wvl = swv[l];
    float om = 1.0f - wvl;
#pragma unroll
    for (int t = 0; t < 4; ++t) {
      f32x2 Sf = S[2 * t] + S[2 * t + 1];
      float St = Sf.x + Sf.y;
      St += __shfl_xor(St, 16, 64);
      St += __shfl_xor(St, 32, 64);
      float mc = C_GLN2 * LOG2F(St);
      F[t] = fmaf(wvl, fmaxf(F[t], 0.0f), om * mc);
    }
  };

  // Manually rotated 2-layer unroll with Am double-buffer prefetch.
  bf16x8 AmA[4], AmB[4];
  load_Am(0, AmA);
#pragma unroll 1
  for (int lp = 0; lp < 3; ++lp) {
    int l0 = 2 * lp, l1 = 2 * lp + 1;
    load_Am(l1, AmB);          // prefetch: issues before l0's poly/exp stages
    layer_body(l0, AmA);
    if (l1 + 1 < LL) load_Am(l1 + 1, AmA);   // prefetch layer l0+2
    layer_body(l1, AmB);
  }

  // ---- smooth-min + store: lane owns point pt0+lane (tile = lane>>4) ----
  {
    int t = lane >> 4;   // wave-uniform per 16-lane group
    float Fv = (t == 0) ? F[0] : (t == 1) ? F[1] : (t == 2) ? F[2] : F[3];
    int idx = pt0 + lane;
    if (idx < NPOINTS) {
      float e = EXP2F(Fv * C_AA);             // exp(-F/0.1)
      out[idx] = C_GLN2 * LOG2F(1.0f + e);    // 0.1 * ln(1 + e)
    }
  }
}

extern "C" void kernel_launch(void* const* d_in, const int* in_sizes, int n_in,
                              void* d_out, int out_size, void* d_ws, size_t ws_size,
                              hipStream_t stream) {
  const float* xs = (const float*)d_in[0];     // [N, D]
  const float* mus = (const float*)d_in[1];    // [L, D, K]
  const float* alphas = (const float*)d_in[2]; // [L, K]
  const float* wsv = (const float*)d_in[3];    // [L]
  float* out = (float*)d_out;
  char* ws = (char*)d_ws;
  (void)ws_size;

  prep_kernel<<<1, 384, 0, stream>>>(mus, alphas, wsv, ws);
  const int blocks = (NPOINTS + PTS_PER_BLOCK - 1) / PTS_PER_BLOCK;  // 1954
  multiinf_kernel<<<blocks, TPB, 0, stream>>>(xs, ws, out);
}

// Round 10
// 94.597 us; speedup vs baseline: 1.0129x; 1.0107x over previous
//
#include <hip/hip_runtime.h>
#include <math.h>

// Problem constants (reference: N=250000, D=16, L=6, K=64, gamma=0.1)
#define NPOINTS 250000
#define LL 6
#define DD 16
#define KK 64

// R21: deferred layer tails + full layer unroll. R7-R9 evidence: the only
// win came from filling the per-layer serial tail (2 dep shfl + log + F-fma,
// ~500cy x 6, unbridgeable across an unroll-1 loop). Fix: layers write only
// lane-local St[l][t]; ALL shuffles (24, batched/pipelined), ALL logs (24,
// trans back-to-back) and the F recurrence run once at the end. Full unroll
// lets the scheduler overlap layer l+1 loads/MFMAs with layer l poly/exp.
#define TPB 128
#define WAVES_PER_BLOCK (TPB / 64)
#define PTS_PER_WAVE 64
#define PTS_PER_BLOCK (WAVES_PER_BLOCK * PTS_PER_WAVE)   // 128

// LDS: per-wave x staging: 64 points * 80 B (32 hi + 32 lo + 16 pad)
#define LDS_BYTES (WAVES_PER_BLOCK * PTS_PER_WAVE * 80)  // 10240

// d_ws layout (bytes):
//  WS_MU: column (l*64+k) as 64 B = 32 B bf16-hi + 32 B bf16-lo, pre-scaled -1/2
//  WS_AV: av[l*64+k] = C_AA*alpha - W0
//  WS_WV: exp(-ws^2) per layer
#define WS_MU 0
#define WS_AV 24576
#define WS_WV 26112

typedef __attribute__((ext_vector_type(8))) short bf16x8;
typedef __attribute__((ext_vector_type(4))) float f32x4;
typedef __attribute__((ext_vector_type(2))) float f32x2;

#if __has_builtin(__builtin_amdgcn_exp2f)
#define EXP2F(x) __builtin_amdgcn_exp2f(x)
#else
#define EXP2F(x) exp2f(x)
#endif
#if __has_builtin(__builtin_amdgcn_logf)
#define LOG2F(x) __builtin_amdgcn_logf(x)
#else
#define LOG2F(x) log2f(x)
#endif

#define C_AA   (-14.426950408889634f)   // -10 * log2(e)
#define C_GLN2 (0.06931471805599453f)   // gamma * ln(2)

// Fused distance->log2 term: with mu pre-scaled by -1/2, MFMA emits x' = -ip/2
// and t2 = (aa - w0) + x'*Vt(x').  Vt = degree-5 poly (error budget: |err(F)|
// <= ~2.6e-4).  Estrin evaluation.
#define W0  17.797117f
#define VT0 (-45.300328f)
#define VT1 (-28.559404f)
#define VT2 (-27.844414f)
#define VT3 (-30.475230f)
#define VT4 (-36.246253f)
#define VT5 (-27.207285f)

__device__ __forceinline__ f32x2 s2(float v) { f32x2 r; r.x = v; r.y = v; return r; }

__device__ __forceinline__ ushort bf16_rne(float f) {
  unsigned u = __float_as_uint(f);
  unsigned r = u + 0x7FFFu + ((u >> 16) & 1u);
  return (ushort)(r >> 16);
}

// t2 = aaw + xp*Vt(xp), Estrin: Vt = P01 + xp^2*(P23 + xp^2*P45)
__device__ __forceinline__ f32x2 poly_t2(f32x2 xp, f32x2 aaw) {
  f32x2 x2  = xp * xp;
  f32x2 p01 = __builtin_elementwise_fma(s2(VT1), xp, s2(VT0));
  f32x2 p23 = __builtin_elementwise_fma(s2(VT3), xp, s2(VT2));
  f32x2 p45 = __builtin_elementwise_fma(s2(VT5), xp, s2(VT4));
  f32x2 qq  = __builtin_elementwise_fma(x2, p45, p23);
  f32x2 V   = __builtin_elementwise_fma(x2, qq, p01);
  return __builtin_elementwise_fma(xp, V, aaw);
}

// pack one float4 (dims 4q..4q+3) of a point into bf16 hi/lo at dst
__device__ __forceinline__ void pack_pt(char* dst, float4 a, int q) {
  ushort h0 = bf16_rne(a.x), h1 = bf16_rne(a.y);
  ushort h2 = bf16_rne(a.z), h3 = bf16_rne(a.w);
  float hf0 = __uint_as_float((unsigned)h0 << 16);
  float hf1 = __uint_as_float((unsigned)h1 << 16);
  float hf2 = __uint_as_float((unsigned)h2 << 16);
  float hf3 = __uint_as_float((unsigned)h3 << 16);
  ushort l0 = bf16_rne(a.x - hf0), l1 = bf16_rne(a.y - hf1);
  ushort l2 = bf16_rne(a.z - hf2), l3 = bf16_rne(a.w - hf3);
  uint2 hwv, lwv;
  hwv.x = (unsigned)h0 | ((unsigned)h1 << 16);
  hwv.y = (unsigned)h2 | ((unsigned)h3 << 16);
  lwv.x = (unsigned)l0 | ((unsigned)l1 << 16);
  lwv.y = (unsigned)l2 | ((unsigned)l3 << 16);
  *(uint2*)(dst + q * 8) = hwv;        // hi words 2q,2q+1
  *(uint2*)(dst + 32 + q * 8) = lwv;   // lo words 2q,2q+1
}

// ---- prep kernel: 1 block, 384 threads; thread t = (layer l, comp k) ----
__global__ __launch_bounds__(384) void
prep_kernel(const float* __restrict__ mus,    // [L, D, K]
            const float* __restrict__ alphas, // [L, K]
            const float* __restrict__ wsv,    // [L]
            char* __restrict__ ws) {
  const int t = threadIdx.x;          // 0..383 == l*64+k
  const float* colp = mus + (t >> 6) * (DD * KK) + (t & 63);
  float v[DD];
  float ss = 0.0f;
#pragma unroll
  for (int d = 0; d < DD; ++d) { v[d] = colp[d * KK]; ss = fmaf(v[d], v[d], ss); }
  float inv = -0.5f / sqrtf(ss);      // normalize AND scale by -1/2 (exact scale)
  unsigned hw[8], lw[8];
#pragma unroll
  for (int i = 0; i < 8; ++i) {
    float a0 = v[2 * i] * inv;
    float a1 = v[2 * i + 1] * inv;
    ushort h0 = bf16_rne(a0), h1 = bf16_rne(a1);
    float hf0 = __uint_as_float((unsigned)h0 << 16);
    float hf1 = __uint_as_float((unsigned)h1 << 16);
    ushort l0 = bf16_rne(a0 - hf0), l1 = bf16_rne(a1 - hf1);
    hw[i] = (unsigned)h0 | ((unsigned)h1 << 16);
    lw[i] = (unsigned)l0 | ((unsigned)l1 << 16);
  }
  uint4* colq = (uint4*)(ws + WS_MU + t * 64);
  colq[0] = make_uint4(hw[0], hw[1], hw[2], hw[3]);
  colq[1] = make_uint4(hw[4], hw[5], hw[6], hw[7]);
  colq[2] = make_uint4(lw[0], lw[1], lw[2], lw[3]);
  colq[3] = make_uint4(lw[4], lw[5], lw[6], lw[7]);
  ((float*)(ws + WS_AV))[t] = fmaf(C_AA, alphas[t], -W0);
  if (t < LL) { float x = wsv[t]; ((float*)(ws + WS_WV))[t] = expf(-x * x); }
}

__global__ __launch_bounds__(TPB, 3) void
multiinf_kernel(const float* __restrict__ xs,
                const char* __restrict__ ws,
                float* __restrict__ out) {
  __shared__ __align__(16) char smem[LDS_BYTES];

  const int tid = threadIdx.x;
  const int wid = tid >> 6;          // wave in block
  const int lane = tid & 63;
  const int c = lane & 15;           // MFMA col: point-in-tile (comp idx for A read)
  const int q = lane >> 4;           // quad
  const int h = q & 1;               // dim half for B (x) reads
  const int pt0 = blockIdx.x * PTS_PER_BLOCK + wid * PTS_PER_WAVE;
  char* sx = smem + wid * (PTS_PER_WAVE * 80);

  // ---- Stage this wave's 64 points (same-wave LDS dep only, no barrier) ----
#pragma unroll
  for (int t = 0; t < 4; ++t) {
    int p = pt0 + 16 * t + c;
    float4 a = make_float4(0.0f, 0.0f, 0.0f, 0.0f);
    if (p < NPOINTS) a = ((const float4*)(xs + (size_t)p * DD))[q];
    pack_pt(sx + (16 * t + c) * 80, a, q);
  }

  // B fragments: loop-invariant; four tiles per wave.
  bf16x8 Bh[4], Bl[4];
#pragma unroll
  for (int t = 0; t < 4; ++t) {
    Bh[t] = *(const bf16x8*)(sx + (16 * t + c) * 80 + h * 16);
    Bl[t] = *(const bf16x8*)(sx + (16 * t + c) * 80 + 32 + h * 16);
  }

  const float* swv = (const float*)(ws + WS_WV);
  const f32x4 zero4 = {0.0f, 0.0f, 0.0f, 0.0f};

  // Lane-local per-layer per-tile sums; ALL cross-lane/trans work deferred.
  float Stv[LL][4];

#pragma unroll   // FULL unroll: no loop branch between layers
  for (int l = 0; l < LL; ++l) {
    bf16x8 Am[4];
    f32x2 aaL[4], aaH[4];
#pragma unroll
    for (int cb = 0; cb < 4; ++cb) {
      Am[cb] = *(const bf16x8*)(ws + WS_MU + (l * 64 + cb * 16 + c) * 64 + q * 16);
      f32x4 a4 = *(const f32x4*)(ws + WS_AV + (l * 64 + cb * 16 + q * 4) * 4);
      aaL[cb].x = a4.x; aaL[cb].y = a4.y;
      aaH[cb].x = a4.z; aaH[cb].y = a4.w;
    }
    f32x2 S01[4], S23[4];
#pragma unroll
    for (int t = 0; t < 4; ++t) { S01[t] = s2(0.0f); S23[t] = s2(0.0f); }
#pragma unroll
    for (int cb = 0; cb < 4; ++cb) {
#pragma unroll
      for (int t = 0; t < 4; ++t) {
        f32x4 acc = __builtin_amdgcn_mfma_f32_16x16x32_bf16(Am[cb], Bh[t], zero4, 0, 0, 0);
        acc = __builtin_amdgcn_mfma_f32_16x16x32_bf16(Am[cb], Bl[t], acc, 0, 0, 0);
        f32x2 x01, x23;
        x01.x = acc[0]; x01.y = acc[1];
        x23.x = acc[2]; x23.y = acc[3];
        f32x2 t2a = poly_t2(x01, aaL[cb]);
        f32x2 t2b = poly_t2(x23, aaH[cb]);
        f32x2 ea, eb;
        ea.x = EXP2F(t2a.x); ea.y = EXP2F(t2a.y);
        eb.x = EXP2F(t2b.x); eb.y = EXP2F(t2b.y);
        S01[t] += ea;
        S23[t] += eb;
      }
    }
#pragma unroll
    for (int t = 0; t < 4; ++t) {
      f32x2 Sf = S01[t] + S23[t];
      Stv[l][t] = Sf.x + Sf.y;     // lane-local; no shuffle/log here
    }
  }

  // ---- Batched cross-lane reduce: 24 independent shfls per round ----
#pragma unroll
  for (int l = 0; l < LL; ++l)
#pragma unroll
    for (int t = 0; t < 4; ++t)
      Stv[l][t] += __shfl_xor(Stv[l][t], 16, 64);
#pragma unroll
  for (int l = 0; l < LL; ++l)
#pragma unroll
    for (int t = 0; t < 4; ++t)
      Stv[l][t] += __shfl_xor(Stv[l][t], 32, 64);

  // ---- Batched logs (24 back-to-back on trans pipe) ----
  float mc[LL][4];
#pragma unroll
  for (int l = 0; l < LL; ++l)
#pragma unroll
    for (int t = 0; t < 4; ++t)
      mc[l][t] = C_GLN2 * LOG2F(Stv[l][t]);

  // ---- Recurrence (cheap, 6 steps x 4 independent tiles) ----
  float F[4] = {0.0f, 0.0f, 0.0f, 0.0f};
#pragma unroll
  for (int l = 0; l < LL; ++l) {
    float wvl = swv[l];
    float om = 1.0f - wvl;
#pragma unroll
    for (int t = 0; t < 4; ++t)
      F[t] = fmaf(wvl, fmaxf(F[t], 0.0f), om * mc[l][t]);
  }

  // ---- smooth-min + store: lane owns point pt0+lane (tile = lane>>4) ----
  {
    int t = lane >> 4;   // wave-uniform per 16-lane group
    float Fv = (t == 0) ? F[0] : (t == 1) ? F[1] : (t == 2) ? F[2] : F[3];
    int idx = pt0 + lane;
    if (idx < NPOINTS) {
      float e = EXP2F(Fv * C_AA);             // exp(-F/0.1)
      out[idx] = C_GLN2 * LOG2F(1.0f + e);    // 0.1 * ln(1 + e)
    }
  }
}

extern "C" void kernel_launch(void* const* d_in, const int* in_sizes, int n_in,
                              void* d_out, int out_size, void* d_ws, size_t ws_size,
                              hipStream_t stream) {
  const float* xs = (const float*)d_in[0];     // [N, D]
  const float* mus = (const float*)d_in[1];    // [L, D, K]
  const float* alphas = (const float*)d_in[2]; // [L, K]
  const float* wsv = (const float*)d_in[3];    // [L]
  float* out = (float*)d_out;
  char* ws = (char*)d_ws;
  (void)ws_size;

  prep_kernel<<<1, 384, 0, stream>>>(mus, alphas, wsv, ws);
  const int blocks = (NPOINTS + PTS_PER_BLOCK - 1) / PTS_PER_BLOCK;  // 1954
  multiinf_kernel<<<blocks, TPB, 0, stream>>>(xs, ws, out);
}